// Round 8
// baseline (217.486 us; speedup 1.0000x reference)
//
#include <hip/hip_runtime.h>
#include <math.h>

#define S_LEN 2048
#define HID   1024
#define NH    16
#define HD    64
#define NM    128
#define CAUG  192
#define NCHW  16            // chunks per wave (KC=32, 4-way wave split)

constexpr float ALPHA = 0.9f;

typedef __attribute__((ext_vector_type(8))) short bf16x8;
typedef __attribute__((ext_vector_type(4))) short bf16x4;
typedef __attribute__((ext_vector_type(4))) float f32x4;
typedef __attribute__((ext_vector_type(4))) int   int4v;

#define MFMA(a,b,c) __builtin_amdgcn_mfma_f32_16x16x32_bf16(a,b,c,0,0,0)

static __device__ inline short f2bf(float f) {
    unsigned u = __float_as_uint(f);
    u += 0x7fffu + ((u >> 16) & 1u);      // RNE
    return (short)(u >> 16);
}
static __device__ inline float bf2f(short s) {
    return __uint_as_float(((unsigned)(unsigned short)s) << 16);
}

// ---------------------------------------------------------------------------
// fp32 -> bf16 conversion: hs + 4 weights, float4-wide; tail range does the
// omega [h][d][m] -> om_t bf16 [h][m][d] transpose.
// ---------------------------------------------------------------------------
__global__ __launch_bounds__(256)
void conv_kernel(const float* __restrict__ hs,
                 const float* __restrict__ Wq, const float* __restrict__ Wk,
                 const float* __restrict__ Wv, const float* __restrict__ Wo,
                 const float* __restrict__ omega,
                 short* __restrict__ hsb, short* __restrict__ wqb, short* __restrict__ wkb,
                 short* __restrict__ wvb, short* __restrict__ wob, short* __restrict__ omtb)
{
    int i = blockIdx.x * 256 + threadIdx.x;           // f4-unit index
    if (i >= 1605632) return;
    if (i >= 1572864) {                               // omega transpose tail
        int j = (i - 1572864) * 4;                    // elem index in [h][d][m]
        int h = j >> 13, rem = j & 8191;
        int d = rem >> 7, m = rem & 127;
        float4 v = *(const float4*)(omega + j);       // 4 consecutive m
        short* dst = omtb + ((h * 128 + m) << 6) + d; // [h][m][d]
        dst[0]       = f2bf(v.x);
        dst[64]      = f2bf(v.y);
        dst[128]     = f2bf(v.z);
        dst[192]     = f2bf(v.w);
        return;
    }
    const float* src; short* dst; int off;
    if (i < 524288) { src = hs; dst = hsb; off = i; }
    else {
        int j = i - 524288;
        int r = j >> 18;              // 0..3
        off = j & 262143;
        src = (r == 0) ? Wq : (r == 1) ? Wk : (r == 2) ? Wv : Wo;
        dst = (r == 0) ? wqb : (r == 1) ? wkb : (r == 2) ? wvb : wob;
    }
    float4 v = ((const float4*)src)[off];
    bf16x4 o; o[0] = f2bf(v.x); o[1] = f2bf(v.y); o[2] = f2bf(v.z); o[3] = f2bf(v.w);
    ((bf16x4*)dst)[off] = o;
}

// ---------------------------------------------------------------------------
// bf16 MFMA GEMM: C = A(2048x1024) @ W(1024x1024)^T + bias
// mode 0: C bf16 [m][1024];  mode 1: C bf16 transposed [n][Mrows];  mode 2: C f32
// ---------------------------------------------------------------------------
__global__ __launch_bounds__(256)
void gemm_mfma(const short* __restrict__ A,
               const short* __restrict__ W0, const float* __restrict__ b0, void* C0,
               const short* __restrict__ W1, const float* __restrict__ b1, void* C1,
               const short* __restrict__ W2, const float* __restrict__ b2, void* C2,
               int m0_, int m1_, int m2_, int Mrows)
{
    const short* W; const float* bias; void* C; int mode;
    if (blockIdx.z == 0)      { W = W0; bias = b0; C = C0; mode = m0_; }
    else if (blockIdx.z == 1) { W = W1; bias = b1; C = C1; mode = m1_; }
    else                      { W = W2; bias = b2; C = C2; mode = m2_; }

    __shared__ short As[128][40];
    __shared__ short Bs[128][40];

    const int tid = threadIdx.x;
    const int wave = tid >> 6, lane = tid & 63;
    const int l15 = lane & 15, l4 = lane >> 4;
    const int wm = wave >> 1, wn = wave & 1;
    const int m0 = blockIdx.y * 128, n0 = blockIdx.x * 128;

    const int srow = (tid >> 2);
    const int scol = (tid & 3) * 16;

    f32x4 acc[4][4];
#pragma unroll
    for (int i = 0; i < 4; ++i)
#pragma unroll
        for (int j = 0; j < 4; ++j) acc[i][j] = (f32x4){0.f,0.f,0.f,0.f};

    int4v apre[2], bpre[2];
#pragma unroll
    for (int it = 0; it < 2; ++it) {
        apre[it] = *(const int4v*)((const char*)A + (size_t)(m0 + srow + it*64) * 2048 + scol);
        bpre[it] = *(const int4v*)((const char*)W + (size_t)(n0 + srow + it*64) * 2048 + scol);
    }

    for (int ks = 0; ks < 32; ++ks) {
        __syncthreads();
#pragma unroll
        for (int it = 0; it < 2; ++it) {
            *(int4v*)((char*)&As[0][0] + (srow + it*64) * 80 + scol) = apre[it];
            *(int4v*)((char*)&Bs[0][0] + (srow + it*64) * 80 + scol) = bpre[it];
        }
        __syncthreads();
        if (ks + 1 < 32) {
            const int kb = (ks + 1) * 64;
#pragma unroll
            for (int it = 0; it < 2; ++it) {
                apre[it] = *(const int4v*)((const char*)A + (size_t)(m0 + srow + it*64) * 2048 + kb + scol);
                bpre[it] = *(const int4v*)((const char*)W + (size_t)(n0 + srow + it*64) * 2048 + kb + scol);
            }
        }
        bf16x8 af[4], bf[4];
#pragma unroll
        for (int mi = 0; mi < 4; ++mi)
            af[mi] = *(const bf16x8*)((const char*)&As[0][0] + (wm*64 + mi*16 + l15) * 80 + l4*16);
#pragma unroll
        for (int nj = 0; nj < 4; ++nj)
            bf[nj] = *(const bf16x8*)((const char*)&Bs[0][0] + (wn*64 + nj*16 + l15) * 80 + l4*16);
#pragma unroll
        for (int mi = 0; mi < 4; ++mi)
#pragma unroll
            for (int nj = 0; nj < 4; ++nj)
                acc[mi][nj] = MFMA(af[mi], bf[nj], acc[mi][nj]);
    }

#pragma unroll
    for (int nj = 0; nj < 4; ++nj) {
        const int nglob = n0 + wn*64 + nj*16 + l15;
        const float bn = bias[nglob];
#pragma unroll
        for (int mi = 0; mi < 4; ++mi) {
            const int mbase = m0 + wm*64 + mi*16 + l4*4;
            if (mode == 0) {
#pragma unroll
                for (int r = 0; r < 4; ++r)
                    ((short*)C)[(size_t)(mbase + r) * 1024 + nglob] = f2bf(acc[mi][nj][r] + bn);
            } else if (mode == 1) {
                bf16x4 pk;
#pragma unroll
                for (int r = 0; r < 4; ++r) pk[r] = f2bf(acc[mi][nj][r] + bn);
                *(bf16x4*)((short*)C + (size_t)nglob * Mrows + mbase) = pk;
            } else {
#pragma unroll
                for (int r = 0; r < 4; ++r)
                    ((float*)C)[(size_t)(mbase + r) * 1024 + nglob] = acc[mi][nj][r] + bn;
            }
        }
    }
}

// ---------------------------------------------------------------------------
// phi2 (MFMA): per block = one (src, head, 64 s-rows)
// ---------------------------------------------------------------------------
__global__ __launch_bounds__(256)
void phi2_kernel(const short* __restrict__ qbuf, const short* __restrict__ kbuf,
                 const short* __restrict__ omtb, const float* __restrict__ rffb,
                 short* __restrict__ Qa, short* __restrict__ Ka)
{
    __shared__ short om[128][72];
    __shared__ float bsh[128];

    const int src = blockIdx.z, h = blockIdx.y;
    const int s0 = blockIdx.x * 64;
    const short* X = src ? kbuf : qbuf;
    short* Out     = src ? Ka : Qa;
    const float fq   = src ? 1.0f : (ALPHA * 0.125f);
    const float fphi = src ? 1.0f : ((1.0f - ALPHA) * 0.125f);

    const int tid = threadIdx.x, wave = tid >> 6, lane = tid & 63;
    const int l15 = lane & 15, l4 = lane >> 4;

    {
        const char* gsrc = (const char*)(omtb + ((size_t)h << 13));
#pragma unroll
        for (int it = 0; it < 4; ++it) {
            int f = tid * 16 + it * 4096;
            int row = f >> 7, colb = f & 127;
            *(int4v*)((char*)&om[0][0] + row * 144 + colb) = *(const int4v*)(gsrc + f);
        }
        if (tid < 128) bsh[tid] = rffb[h * 128 + tid];
    }
    __syncthreads();

    const int srow = s0 + wave * 16 + l15;

    bf16x8 xf[2];
#pragma unroll
    for (int cs = 0; cs < 2; ++cs)
        xf[cs] = *(const bf16x8*)(X + (size_t)srow * HID + h * HD + cs * 32 + l4 * 8);

    float ss = 0.f;
#pragma unroll
    for (int cs = 0; cs < 2; ++cs)
#pragma unroll
        for (int j = 0; j < 8; ++j) { float v = bf2f(xf[cs][j]); ss = fmaf(v, v, ss); }
    ss += __shfl_xor(ss, 16);
    ss += __shfl_xor(ss, 32);
    const float inv = 1.0f / (sqrtf(ss) + 1e-6f);

    bf16x8 qn[2];
#pragma unroll
    for (int cs = 0; cs < 2; ++cs) {
        bf16x8 o, w;
#pragma unroll
        for (int j = 0; j < 8; ++j) {
            float v = bf2f(xf[cs][j]);
            o[j] = f2bf(v * inv);
            w[j] = f2bf(v * fq);
        }
        qn[cs] = o;
        *(bf16x8*)(Out + ((size_t)h * S_LEN + srow) * CAUG + cs * 32 + l4 * 8) = w;
    }

    f32x4 pacc[8];
#pragma unroll
    for (int t = 0; t < 8; ++t) pacc[t] = (f32x4){0.f,0.f,0.f,0.f};
#pragma unroll
    for (int t = 0; t < 8; ++t)
#pragma unroll
        for (int cs = 0; cs < 2; ++cs) {
            bf16x8 bf = *(const bf16x8*)((const char*)&om[0][0] + (t*16 + l15) * 144 + cs*64 + l4*16);
            pacc[t] = MFMA(qn[cs], bf, pacc[t]);
        }

    float ph[8][4];
    float ps[4] = {0.f, 0.f, 0.f, 0.f};
#pragma unroll
    for (int t = 0; t < 8; ++t) {
        const float bv = bsh[t * 16 + l15];
#pragma unroll
        for (int r = 0; r < 4; ++r) {
            float p = pacc[t][r] + bv;
            float c = 0.125f * __cosf(p);
            ph[t][r] = c;
            ps[r] = fmaf(c, c, ps[r]);
        }
    }
#pragma unroll
    for (int r = 0; r < 4; ++r) {
        ps[r] += __shfl_xor(ps[r], 1);
        ps[r] += __shfl_xor(ps[r], 2);
        ps[r] += __shfl_xor(ps[r], 4);
        ps[r] += __shfl_xor(ps[r], 8);
    }
    float inv2[4];
#pragma unroll
    for (int r = 0; r < 4; ++r) inv2[r] = fphi / (sqrtf(ps[r]) + 1e-6f);

#pragma unroll
    for (int t = 0; t < 8; ++t)
#pragma unroll
        for (int r = 0; r < 4; ++r)
            Out[((size_t)h * S_LEN + s0 + wave * 16 + l4 * 4 + r) * CAUG + 64 + t * 16 + l15]
                = f2bf(ph[t][r] * inv2[r]);
}

// ---------------------------------------------------------------------------
// MFMA flash attention, cache-direct K/V with ONE-CHUNK REGISTER PREFETCH.
// Block = 32 q rows; 4 waves each own all 32 q over a quarter of the K range
// (16 chunks of 32 kpos).  While computing chunk i from register fragments,
// the fragments of chunk i+1 are loading (ping-pong kA/kB, vA/vB).  Static-max
// softmax; P crosses lanes via per-wave LDS slab (no barriers in main loop);
// partials combined in LDS at the end.  Grid 64x16 = 1024 blocks.
// ---------------------------------------------------------------------------
__global__ __launch_bounds__(256, 2)
void flash_mfma(const short* __restrict__ Qa, const short* __restrict__ Ka,
                const short* __restrict__ vt, const float* __restrict__ mask,
                short* __restrict__ ctxb)
{
    // [0, 10240): Pl[4][32][40] bf16 (per-wave P slabs, 80B rows)
    // after-loop: scrO f32 [3][32][68] @ 0, scrL f32 [3][32] @ 26112
    __shared__ char smem[26496];

    const int tid = threadIdx.x;
    const int wave = tid >> 6, lane = tid & 63;
    const int l15 = lane & 15, l4 = lane >> 4;
    const int h = blockIdx.y;
    const int q0 = blockIdx.x * 32;

    char* PlW = smem + wave * 2560;    // this wave's 32x80B P slab

    // Q' fragments: 32 q rows (same for all 4 waves; L1/L2-served)
    bf16x8 qf[2][6];
#pragma unroll
    for (int qj = 0; qj < 2; ++qj)
#pragma unroll
        for (int cs = 0; cs < 6; ++cs)
            qf[qj][cs] = *(const bf16x8*)(Qa + ((size_t)h * 2048 + q0 + qj*16 + l15) * CAUG + cs*32 + l4*8);

    f32x4 oacc[4][2];
#pragma unroll
    for (int di = 0; di < 4; ++di)
#pragma unroll
        for (int qj = 0; qj < 2; ++qj) oacc[di][qj] = (f32x4){0.f,0.f,0.f,0.f};
    float lsum[2] = {0.f, 0.f};

    const char* Kg = (const char*)(Ka + (size_t)h * 2048 * CAUG);   // rows 384B
    const char* Vg = (const char*)(vt + (size_t)h * 64 * 2048);     // rows 4096B

    // fragment loaders (global -> regs, fragment layout directly)
    auto loadK = [&](bf16x8 (&dst)[12], int kt) {
        const char* kb = Kg + (size_t)kt * 32 * 384;
#pragma unroll
        for (int cs = 0; cs < 6; ++cs)
#pragma unroll
            for (int fi = 0; fi < 2; ++fi)
                dst[cs*2 + fi] = *(const bf16x8*)(kb + (fi*16 + l15)*384 + cs*64 + l4*16);
    };
    auto loadV = [&](bf16x8 (&dst)[4], int kt) {
#pragma unroll
        for (int di = 0; di < 4; ++di)
            dst[di] = *(const bf16x8*)(Vg + (size_t)(di*16 + l15)*4096 + kt*64 + l4*16);
    };
    auto computeChunk = [&](const bf16x8 (&kf)[12], const bf16x8 (&vf)[4], int kt) {
        // ---- scores S^T (32 kpos x 32 q) ----
        f32x4 sacc[2][2];
#pragma unroll
        for (int fi = 0; fi < 2; ++fi)
#pragma unroll
            for (int qj = 0; qj < 2; ++qj) sacc[fi][qj] = (f32x4){0.f,0.f,0.f,0.f};
#pragma unroll
        for (int cs = 0; cs < 6; ++cs)
#pragma unroll
            for (int fi = 0; fi < 2; ++fi)
#pragma unroll
                for (int qj = 0; qj < 2; ++qj)
                    sacc[fi][qj] = MFMA(kf[cs*2 + fi], qf[qj][cs], sacc[fi][qj]);
        // ---- static-max softmax: p = exp(s + mask); accumulate l ----
#pragma unroll
        for (int fi = 0; fi < 2; ++fi) {
            float4 mk = *(const float4*)&mask[kt*32 + fi*16 + l4*4];
            float mv[4] = {mk.x * -10000.f, mk.y * -10000.f, mk.z * -10000.f, mk.w * -10000.f};
#pragma unroll
            for (int qj = 0; qj < 2; ++qj) {
                bf16x4 pk;
#pragma unroll
                for (int r = 0; r < 4; ++r) {
                    float p = __expf(sacc[fi][qj][r] + mv[r]);
                    lsum[qj] += p;
                    pk[r] = f2bf(p);
                }
                *(bf16x4*)(PlW + (qj*16 + l15)*80 + fi*32 + l4*8) = pk;
            }
        }
        // ---- PV: O^T += V^T . P^T ----
        bf16x8 pb[2];
#pragma unroll
        for (int qj = 0; qj < 2; ++qj)
            pb[qj] = *(const bf16x8*)(PlW + (qj*16 + l15)*80 + l4*16);
#pragma unroll
        for (int di = 0; di < 4; ++di)
#pragma unroll
            for (int qj = 0; qj < 2; ++qj)
                oacc[di][qj] = MFMA(vf[di], pb[qj], oacc[di][qj]);
    };

    // ---- main loop: ping-pong register double-buffer, zero barriers ----
    bf16x8 kA[12], kB[12], vA[4], vB[4];
    const int base = wave * NCHW;
    loadK(kA, base); loadV(vA, base);
#pragma unroll 2
    for (int i = 0; i < NCHW; i += 2) {
        const int n1 = base + i + 1;
        loadK(kB, n1); loadV(vB, n1);
        computeChunk(kA, vA, base + i);
        const int n2 = (i + 2 < NCHW) ? (base + i + 2) : n1;  // tail: harmless reload
        loadK(kA, n2); loadV(vA, n2);
        computeChunk(kB, vB, n1);
    }

    // reduce l across the 4 kpos lane-groups
#pragma unroll
    for (int qj = 0; qj < 2; ++qj) {
        lsum[qj] += __shfl_xor(lsum[qj], 16);
        lsum[qj] += __shfl_xor(lsum[qj], 32);
    }

    // ---- combine the 4 wave partials via LDS ----
    __syncthreads();
    float* scrO = (float*)smem;                 // [3][32][68]
    float* scrL = (float*)(smem + 26112);       // [3][32]
    if (wave > 0) {
#pragma unroll
        for (int qj = 0; qj < 2; ++qj) {
#pragma unroll
            for (int di = 0; di < 4; ++di)
                *(f32x4*)&scrO[(size_t)((wave-1)*32 + qj*16 + l15)*68 + di*16 + l4*4] = oacc[di][qj];
            if (l4 == 0) scrL[(wave-1)*32 + qj*16 + l15] = lsum[qj];
        }
    }
    __syncthreads();
    if (wave == 0) {
#pragma unroll
        for (int qj = 0; qj < 2; ++qj) {
            float l = lsum[qj];
#pragma unroll
            for (int k = 0; k < 3; ++k) l += scrL[k*32 + qj*16 + l15];
            const float inv = 1.0f / l;
            const int s = q0 + qj*16 + l15;
#pragma unroll
            for (int di = 0; di < 4; ++di) {
                f32x4 o = oacc[di][qj];
#pragma unroll
                for (int k = 0; k < 3; ++k)
                    o += *(const f32x4*)&scrO[(size_t)(k*32 + qj*16 + l15)*68 + di*16 + l4*4];
                bf16x4 ob;
#pragma unroll
                for (int r = 0; r < 4; ++r) ob[r] = f2bf(o[r] * inv);
                *(bf16x4*)(ctxb + (size_t)s * HID + h*64 + di*16 + l4*4) = ob;
            }
        }
    }
}

// ---------------------------------------------------------------------------
extern "C" void kernel_launch(void* const* d_in, const int* in_sizes, int n_in,
                              void* d_out, int out_size, void* d_ws, size_t ws_size,
                              hipStream_t stream)
{
    const float* hs    = (const float*)d_in[0];
    const float* mask  = (const float*)d_in[1];
    const float* Wq    = (const float*)d_in[2];
    const float* bq    = (const float*)d_in[3];
    const float* Wk    = (const float*)d_in[4];
    const float* bk    = (const float*)d_in[5];
    const float* Wv    = (const float*)d_in[6];
    const float* bv    = (const float*)d_in[7];
    const float* Wo    = (const float*)d_in[8];
    const float* bo    = (const float*)d_in[9];
    const float* omega = (const float*)d_in[10];
    const float* rffb  = (const float*)d_in[11];
    float* out = (float*)d_out;

    short* wsS = (short*)d_ws;
    short* hsb = wsS;                       // 2,097,152
    short* wqb = hsb + 2097152;             // 1,048,576
    short* wkb = wqb + 1048576;
    short* wvb = wkb + 1048576;
    short* wob = wvb + 1048576;
    short* qb  = wob + 1048576;             // 2,097,152
    short* kb  = qb  + 2097152;
    short* vtb = kb  + 2097152;             // 2,097,152  [h][d][s]
    short* ctxb= vtb + 2097152;             // 2,097,152
    short* QaB = ctxb+ 2097152;             // 6,291,456  [h][s][192]
    short* KaB = QaB + 6291456;
    short* omtb= KaB + 6291456;             // 131,072    [h][m][d]

    conv_kernel<<<6272, 256, 0, stream>>>(hs, Wq, Wk, Wv, Wo, omega,
                                          hsb, wqb, wkb, wvb, wob, omtb);
    gemm_mfma<<<dim3(8, 16, 3), 256, 0, stream>>>(hsb, wqb, bq, qb, wkb, bk, kb, wvb, bv, vtb,
                                                  0, 0, 1, S_LEN);
    phi2_kernel<<<dim3(32, 16, 2), 256, 0, stream>>>(qb, kb, omtb, rffb, QaB, KaB);
    flash_mfma<<<dim3(64, 16), 256, 0, stream>>>(QaB, KaB, vtb, mask, ctxb);
    gemm_mfma<<<dim3(8, 16, 1), 256, 0, stream>>>(ctxb, wob, bo, out, wob, bo, out, wob, bo, out,
                                                  2, 2, 2, S_LEN);
}

// Round 9
// 135.773 us; speedup vs baseline: 1.6018x; 1.6018x over previous
//
#include <hip/hip_runtime.h>
#include <math.h>

#define S_LEN 2048
#define HID   1024
#define NH    16
#define HD    64
#define NM    128
#define CAUG  192
#define NCH   32            // chunks (KC=32) per wave-group; 2 groups cover 2048

constexpr float ALPHA = 0.9f;

typedef __attribute__((ext_vector_type(8))) short bf16x8;
typedef __attribute__((ext_vector_type(4))) short bf16x4;
typedef __attribute__((ext_vector_type(4))) float f32x4;
typedef __attribute__((ext_vector_type(4))) int   int4v;

#define MFMA(a,b,c) __builtin_amdgcn_mfma_f32_16x16x32_bf16(a,b,c,0,0,0)

static __device__ inline short f2bf(float f) {
    unsigned u = __float_as_uint(f);
    u += 0x7fffu + ((u >> 16) & 1u);      // RNE
    return (short)(u >> 16);
}
static __device__ inline float bf2f(short s) {
    return __uint_as_float(((unsigned)(unsigned short)s) << 16);
}

// ---------------------------------------------------------------------------
// fp32 -> bf16 conversion: hs + 4 weights, float4-wide; tail range does the
// omega [h][d][m] -> om_t bf16 [h][m][d] transpose.
// ---------------------------------------------------------------------------
__global__ __launch_bounds__(256)
void conv_kernel(const float* __restrict__ hs,
                 const float* __restrict__ Wq, const float* __restrict__ Wk,
                 const float* __restrict__ Wv, const float* __restrict__ Wo,
                 const float* __restrict__ omega,
                 short* __restrict__ hsb, short* __restrict__ wqb, short* __restrict__ wkb,
                 short* __restrict__ wvb, short* __restrict__ wob, short* __restrict__ omtb)
{
    int i = blockIdx.x * 256 + threadIdx.x;           // f4-unit index
    if (i >= 1605632) return;
    if (i >= 1572864) {                               // omega transpose tail
        int j = (i - 1572864) * 4;                    // elem index in [h][d][m]
        int h = j >> 13, rem = j & 8191;
        int d = rem >> 7, m = rem & 127;
        float4 v = *(const float4*)(omega + j);       // 4 consecutive m
        short* dst = omtb + ((h * 128 + m) << 6) + d; // [h][m][d]
        dst[0]       = f2bf(v.x);
        dst[64]      = f2bf(v.y);
        dst[128]     = f2bf(v.z);
        dst[192]     = f2bf(v.w);
        return;
    }
    const float* src; short* dst; int off;
    if (i < 524288) { src = hs; dst = hsb; off = i; }
    else {
        int j = i - 524288;
        int r = j >> 18;              // 0..3
        off = j & 262143;
        src = (r == 0) ? Wq : (r == 1) ? Wk : (r == 2) ? Wv : Wo;
        dst = (r == 0) ? wqb : (r == 1) ? wkb : (r == 2) ? wvb : wob;
    }
    float4 v = ((const float4*)src)[off];
    bf16x4 o; o[0] = f2bf(v.x); o[1] = f2bf(v.y); o[2] = f2bf(v.z); o[3] = f2bf(v.w);
    ((bf16x4*)dst)[off] = o;
}

// ---------------------------------------------------------------------------
// bf16 MFMA GEMM: C = A(2048x1024) @ W(1024x1024)^T + bias
// mode 0: C bf16 [m][1024];  mode 1: C bf16 transposed [n][Mrows];  mode 2: C f32
// ---------------------------------------------------------------------------
__global__ __launch_bounds__(256)
void gemm_mfma(const short* __restrict__ A,
               const short* __restrict__ W0, const float* __restrict__ b0, void* C0,
               const short* __restrict__ W1, const float* __restrict__ b1, void* C1,
               const short* __restrict__ W2, const float* __restrict__ b2, void* C2,
               int m0_, int m1_, int m2_, int Mrows)
{
    const short* W; const float* bias; void* C; int mode;
    if (blockIdx.z == 0)      { W = W0; bias = b0; C = C0; mode = m0_; }
    else if (blockIdx.z == 1) { W = W1; bias = b1; C = C1; mode = m1_; }
    else                      { W = W2; bias = b2; C = C2; mode = m2_; }

    __shared__ short As[128][40];
    __shared__ short Bs[128][40];

    const int tid = threadIdx.x;
    const int wave = tid >> 6, lane = tid & 63;
    const int l15 = lane & 15, l4 = lane >> 4;
    const int wm = wave >> 1, wn = wave & 1;
    const int m0 = blockIdx.y * 128, n0 = blockIdx.x * 128;

    const int srow = (tid >> 2);
    const int scol = (tid & 3) * 16;

    f32x4 acc[4][4];
#pragma unroll
    for (int i = 0; i < 4; ++i)
#pragma unroll
        for (int j = 0; j < 4; ++j) acc[i][j] = (f32x4){0.f,0.f,0.f,0.f};

    int4v apre[2], bpre[2];
#pragma unroll
    for (int it = 0; it < 2; ++it) {
        apre[it] = *(const int4v*)((const char*)A + (size_t)(m0 + srow + it*64) * 2048 + scol);
        bpre[it] = *(const int4v*)((const char*)W + (size_t)(n0 + srow + it*64) * 2048 + scol);
    }

    for (int ks = 0; ks < 32; ++ks) {
        __syncthreads();
#pragma unroll
        for (int it = 0; it < 2; ++it) {
            *(int4v*)((char*)&As[0][0] + (srow + it*64) * 80 + scol) = apre[it];
            *(int4v*)((char*)&Bs[0][0] + (srow + it*64) * 80 + scol) = bpre[it];
        }
        __syncthreads();
        if (ks + 1 < 32) {
            const int kb = (ks + 1) * 64;
#pragma unroll
            for (int it = 0; it < 2; ++it) {
                apre[it] = *(const int4v*)((const char*)A + (size_t)(m0 + srow + it*64) * 2048 + kb + scol);
                bpre[it] = *(const int4v*)((const char*)W + (size_t)(n0 + srow + it*64) * 2048 + kb + scol);
            }
        }
        bf16x8 af[4], bf[4];
#pragma unroll
        for (int mi = 0; mi < 4; ++mi)
            af[mi] = *(const bf16x8*)((const char*)&As[0][0] + (wm*64 + mi*16 + l15) * 80 + l4*16);
#pragma unroll
        for (int nj = 0; nj < 4; ++nj)
            bf[nj] = *(const bf16x8*)((const char*)&Bs[0][0] + (wn*64 + nj*16 + l15) * 80 + l4*16);
#pragma unroll
        for (int mi = 0; mi < 4; ++mi)
#pragma unroll
            for (int nj = 0; nj < 4; ++nj)
                acc[mi][nj] = MFMA(af[mi], bf[nj], acc[mi][nj]);
    }

#pragma unroll
    for (int nj = 0; nj < 4; ++nj) {
        const int nglob = n0 + wn*64 + nj*16 + l15;
        const float bn = bias[nglob];
#pragma unroll
        for (int mi = 0; mi < 4; ++mi) {
            const int mbase = m0 + wm*64 + mi*16 + l4*4;
            if (mode == 0) {
#pragma unroll
                for (int r = 0; r < 4; ++r)
                    ((short*)C)[(size_t)(mbase + r) * 1024 + nglob] = f2bf(acc[mi][nj][r] + bn);
            } else if (mode == 1) {
                bf16x4 pk;
#pragma unroll
                for (int r = 0; r < 4; ++r) pk[r] = f2bf(acc[mi][nj][r] + bn);
                *(bf16x4*)((short*)C + (size_t)nglob * Mrows + mbase) = pk;
            } else {
#pragma unroll
                for (int r = 0; r < 4; ++r)
                    ((float*)C)[(size_t)(mbase + r) * 1024 + nglob] = acc[mi][nj][r] + bn;
            }
        }
    }
}

// ---------------------------------------------------------------------------
// phi2 (MFMA): per block = one (src, head, 64 s-rows)
// ---------------------------------------------------------------------------
__global__ __launch_bounds__(256)
void phi2_kernel(const short* __restrict__ qbuf, const short* __restrict__ kbuf,
                 const short* __restrict__ omtb, const float* __restrict__ rffb,
                 short* __restrict__ Qa, short* __restrict__ Ka)
{
    __shared__ short om[128][72];
    __shared__ float bsh[128];

    const int src = blockIdx.z, h = blockIdx.y;
    const int s0 = blockIdx.x * 64;
    const short* X = src ? kbuf : qbuf;
    short* Out     = src ? Ka : Qa;
    const float fq   = src ? 1.0f : (ALPHA * 0.125f);
    const float fphi = src ? 1.0f : ((1.0f - ALPHA) * 0.125f);

    const int tid = threadIdx.x, wave = tid >> 6, lane = tid & 63;
    const int l15 = lane & 15, l4 = lane >> 4;

    {
        const char* gsrc = (const char*)(omtb + ((size_t)h << 13));
#pragma unroll
        for (int it = 0; it < 4; ++it) {
            int f = tid * 16 + it * 4096;
            int row = f >> 7, colb = f & 127;
            *(int4v*)((char*)&om[0][0] + row * 144 + colb) = *(const int4v*)(gsrc + f);
        }
        if (tid < 128) bsh[tid] = rffb[h * 128 + tid];
    }
    __syncthreads();

    const int srow = s0 + wave * 16 + l15;

    bf16x8 xf[2];
#pragma unroll
    for (int cs = 0; cs < 2; ++cs)
        xf[cs] = *(const bf16x8*)(X + (size_t)srow * HID + h * HD + cs * 32 + l4 * 8);

    float ss = 0.f;
#pragma unroll
    for (int cs = 0; cs < 2; ++cs)
#pragma unroll
        for (int j = 0; j < 8; ++j) { float v = bf2f(xf[cs][j]); ss = fmaf(v, v, ss); }
    ss += __shfl_xor(ss, 16);
    ss += __shfl_xor(ss, 32);
    const float inv = 1.0f / (sqrtf(ss) + 1e-6f);

    bf16x8 qn[2];
#pragma unroll
    for (int cs = 0; cs < 2; ++cs) {
        bf16x8 o, w;
#pragma unroll
        for (int j = 0; j < 8; ++j) {
            float v = bf2f(xf[cs][j]);
            o[j] = f2bf(v * inv);
            w[j] = f2bf(v * fq);
        }
        qn[cs] = o;
        *(bf16x8*)(Out + ((size_t)h * S_LEN + srow) * CAUG + cs * 32 + l4 * 8) = w;
    }

    f32x4 pacc[8];
#pragma unroll
    for (int t = 0; t < 8; ++t) pacc[t] = (f32x4){0.f,0.f,0.f,0.f};
#pragma unroll
    for (int t = 0; t < 8; ++t)
#pragma unroll
        for (int cs = 0; cs < 2; ++cs) {
            bf16x8 bf = *(const bf16x8*)((const char*)&om[0][0] + (t*16 + l15) * 144 + cs*64 + l4*16);
            pacc[t] = MFMA(qn[cs], bf, pacc[t]);
        }

    float ph[8][4];
    float ps[4] = {0.f, 0.f, 0.f, 0.f};
#pragma unroll
    for (int t = 0; t < 8; ++t) {
        const float bv = bsh[t * 16 + l15];
#pragma unroll
        for (int r = 0; r < 4; ++r) {
            float p = pacc[t][r] + bv;
            float c = 0.125f * __cosf(p);
            ph[t][r] = c;
            ps[r] = fmaf(c, c, ps[r]);
        }
    }
#pragma unroll
    for (int r = 0; r < 4; ++r) {
        ps[r] += __shfl_xor(ps[r], 1);
        ps[r] += __shfl_xor(ps[r], 2);
        ps[r] += __shfl_xor(ps[r], 4);
        ps[r] += __shfl_xor(ps[r], 8);
    }
    float inv2[4];
#pragma unroll
    for (int r = 0; r < 4; ++r) inv2[r] = fphi / (sqrtf(ps[r]) + 1e-6f);

#pragma unroll
    for (int t = 0; t < 8; ++t)
#pragma unroll
        for (int r = 0; r < 4; ++r)
            Out[((size_t)h * S_LEN + s0 + wave * 16 + l4 * 4 + r) * CAUG + 64 + t * 16 + l15]
                = f2bf(ph[t][r] * inv2[r]);
}

// ---------------------------------------------------------------------------
// MFMA flash attention (R6 structure + double-buffered K staging).
// 2 wave-groups: group g covers chunks [g*32, g*32+32); each of its 2 waves
// owns 32 q rows (block q-tile 64).  Static-max softmax (p = exp(s+mask)).
// K staged in LDS, DOUBLE-BUFFERED -> one barrier per chunk, ds_write of
// chunk i+1 overlaps compute of chunk i.  V via 2-entry register ping-pong
// (no LDS).  P crosses lanes via per-wave LDS slab.  Combine in LDS.
// Grid 32x16 = 512 blocks = 2 blocks/CU (61.4 KB LDS).
// ---------------------------------------------------------------------------
__global__ __launch_bounds__(256, 2)
void flash_mfma(const short* __restrict__ Qa, const short* __restrict__ Ka,
                const short* __restrict__ vt, const float* __restrict__ mask,
                short* __restrict__ ctxb)
{
    // layout:
    //   [0, 10240): Pl[4][32][80B]  per-wave P slabs
    //   [10240, 61440): K bufs: group g, buf b at 10240 + (g*2+b)*12800
    //   combine scratch (after loop): scrO f32[3][32][68] @ 10240, scrL @ 36352
    __shared__ char smem[61440];

    const int tid = threadIdx.x;
    const int wave = tid >> 6, lane = tid & 63;
    const int l15 = lane & 15, l4 = lane >> 4;
    const int g = wave >> 1, sub = wave & 1;
    const int h = blockIdx.y;
    const int q0 = blockIdx.x * 64 + sub * 32;

    char* PlW  = smem + wave * 2560;
    char* bufA = smem + 10240 + g * 25600;
    char* bufB = bufA + 12800;

    // Q' fragments: 32 q rows per wave
    bf16x8 qf[2][6];
#pragma unroll
    for (int qj = 0; qj < 2; ++qj)
#pragma unroll
        for (int cs = 0; cs < 6; ++cs)
            qf[qj][cs] = *(const bf16x8*)(Qa + ((size_t)h * 2048 + q0 + qj*16 + l15) * CAUG + cs*32 + l4*8);

    f32x4 oacc[4][2];
#pragma unroll
    for (int di = 0; di < 4; ++di)
#pragma unroll
        for (int qj = 0; qj < 2; ++qj) oacc[di][qj] = (f32x4){0.f,0.f,0.f,0.f};
    float lsum[2] = {0.f, 0.f};

    // staging geometry: 128 threads of the group stage 12288 B (6 x 16B each)
    const int t = tid & 127;
    int kr[6], kcb[6];
#pragma unroll
    for (int it = 0; it < 6; ++it) { int f = t*16 + it*2048; kr[it] = f/384; kcb[it] = f%384; }

    const char* Kg = (const char*)(Ka + (size_t)h * 2048 * CAUG);   // rows 384B
    const char* Vg = (const char*)(vt + (size_t)h * 64 * 2048);     // rows 4096B
    const int base = g * NCH;

    int4v kpre[6];
    bf16x8 vA[4], vB[4];

    auto loadKpre = [&](int kt) {
        const char* kb = Kg + (size_t)kt * 12288;
#pragma unroll
        for (int it = 0; it < 6; ++it)
            kpre[it] = *(const int4v*)(kb + (size_t)kr[it]*384 + kcb[it]);
    };
    auto writeStage = [&](char* buf) {
#pragma unroll
        for (int it = 0; it < 6; ++it)
            *(int4v*)(buf + kr[it]*400 + kcb[it]) = kpre[it];
    };
    auto loadV = [&](bf16x8 (&dst)[4], int kt) {
#pragma unroll
        for (int di = 0; di < 4; ++di)
            dst[di] = *(const bf16x8*)(Vg + (size_t)(di*16 + l15)*4096 + kt*64 + l4*16);
    };
    auto computeChunk = [&](const char* buf, const bf16x8 (&vf)[4], int kt) {
        // ---- scores S^T (32 kpos x 32 q) ----
        f32x4 sacc[2][2];
#pragma unroll
        for (int fi = 0; fi < 2; ++fi)
#pragma unroll
            for (int qj = 0; qj < 2; ++qj) sacc[fi][qj] = (f32x4){0.f,0.f,0.f,0.f};
#pragma unroll
        for (int cs = 0; cs < 6; ++cs) {
            bf16x8 ka[2];
#pragma unroll
            for (int fi = 0; fi < 2; ++fi)
                ka[fi] = *(const bf16x8*)(buf + (fi*16 + l15)*400 + cs*64 + l4*16);
#pragma unroll
            for (int fi = 0; fi < 2; ++fi)
#pragma unroll
                for (int qj = 0; qj < 2; ++qj)
                    sacc[fi][qj] = MFMA(ka[fi], qf[qj][cs], sacc[fi][qj]);
        }
        // ---- static-max softmax: p = exp(s + mask) ----
#pragma unroll
        for (int fi = 0; fi < 2; ++fi) {
            float4 mk = *(const float4*)&mask[kt*32 + fi*16 + l4*4];
            float mv[4] = {mk.x * -10000.f, mk.y * -10000.f, mk.z * -10000.f, mk.w * -10000.f};
#pragma unroll
            for (int qj = 0; qj < 2; ++qj) {
                bf16x4 pk;
#pragma unroll
                for (int r = 0; r < 4; ++r) {
                    float p = __expf(sacc[fi][qj][r] + mv[r]);
                    lsum[qj] += p;
                    pk[r] = f2bf(p);
                }
                *(bf16x4*)(PlW + (qj*16 + l15)*80 + fi*32 + l4*8) = pk;
            }
        }
        // ---- PV: O^T += V^T . P^T ----
        bf16x8 pb[2];
#pragma unroll
        for (int qj = 0; qj < 2; ++qj)
            pb[qj] = *(const bf16x8*)(PlW + (qj*16 + l15)*80 + l4*16);
#pragma unroll
        for (int di = 0; di < 4; ++di)
#pragma unroll
            for (int qj = 0; qj < 2; ++qj)
                oacc[di][qj] = MFMA(vf[di], pb[qj], oacc[di][qj]);
    };

    // prologue: stage chunk base+0 into bufA, V into vA
    loadKpre(base);
    writeStage(bufA);
    loadV(vA, base);
    __syncthreads();

    for (int i = 0; i < NCH; i += 2) {
        // --- iter A: compute chunk i from bufA/vA; stage i+1 -> bufB/vB ---
        loadKpre(base + i + 1);                    // i+1 <= 31 always valid
        loadV(vB, base + i + 1);
        computeChunk(bufA, vA, base + i);
        writeStage(bufB);
        __syncthreads();
        // --- iter B: compute chunk i+1 from bufB/vB; stage i+2 -> bufA/vA ---
        if (i + 2 < NCH) {
            loadKpre(base + i + 2);
            loadV(vA, base + i + 2);
        }
        computeChunk(bufB, vB, base + i + 1);
        if (i + 2 < NCH) writeStage(bufA);
        __syncthreads();
    }

    // reduce l across the 4 kpos lane-groups
#pragma unroll
    for (int qj = 0; qj < 2; ++qj) {
        lsum[qj] += __shfl_xor(lsum[qj], 16);
        lsum[qj] += __shfl_xor(lsum[qj], 32);
    }

    // ---- combine the two K-groups via LDS scratch (reuse K-buf region) ----
    float* scrO = (float*)(smem + 10240);       // [2][32][68] used as [k][row]
    float* scrL = (float*)(smem + 36352);       // [2][32]
    if (g == 1) {
#pragma unroll
        for (int qj = 0; qj < 2; ++qj) {
#pragma unroll
            for (int di = 0; di < 4; ++di)
                *(f32x4*)&scrO[(size_t)(sub*32 + qj*16 + l15)*68 + di*16 + l4*4] = oacc[di][qj];
            if (l4 == 0) scrL[sub*32 + qj*16 + l15] = lsum[qj];
        }
    }
    __syncthreads();
    if (g == 0) {
#pragma unroll
        for (int qj = 0; qj < 2; ++qj) {
            const float l = lsum[qj] + scrL[sub*32 + qj*16 + l15];
            const float inv = 1.0f / l;
            const int s = q0 + qj*16 + l15;
#pragma unroll
            for (int di = 0; di < 4; ++di) {
                f32x4 o2 = *(const f32x4*)&scrO[(size_t)(sub*32 + qj*16 + l15)*68 + di*16 + l4*4];
                bf16x4 ob;
#pragma unroll
                for (int r = 0; r < 4; ++r) ob[r] = f2bf((oacc[di][qj][r] + o2[r]) * inv);
                *(bf16x4*)(ctxb + (size_t)s * HID + h*64 + di*16 + l4*4) = ob;
            }
        }
    }
}

// ---------------------------------------------------------------------------
extern "C" void kernel_launch(void* const* d_in, const int* in_sizes, int n_in,
                              void* d_out, int out_size, void* d_ws, size_t ws_size,
                              hipStream_t stream)
{
    const float* hs    = (const float*)d_in[0];
    const float* mask  = (const float*)d_in[1];
    const float* Wq    = (const float*)d_in[2];
    const float* bq    = (const float*)d_in[3];
    const float* Wk    = (const float*)d_in[4];
    const float* bk    = (const float*)d_in[5];
    const float* Wv    = (const float*)d_in[6];
    const float* bv    = (const float*)d_in[7];
    const float* Wo    = (const float*)d_in[8];
    const float* bo    = (const float*)d_in[9];
    const float* omega = (const float*)d_in[10];
    const float* rffb  = (const float*)d_in[11];
    float* out = (float*)d_out;

    short* wsS = (short*)d_ws;
    short* hsb = wsS;                       // 2,097,152
    short* wqb = hsb + 2097152;             // 1,048,576
    short* wkb = wqb + 1048576;
    short* wvb = wkb + 1048576;
    short* wob = wvb + 1048576;
    short* qb  = wob + 1048576;             // 2,097,152
    short* kb  = qb  + 2097152;
    short* vtb = kb  + 2097152;             // 2,097,152  [h][d][s]
    short* ctxb= vtb + 2097152;             // 2,097,152
    short* QaB = ctxb+ 2097152;             // 6,291,456  [h][s][192]
    short* KaB = QaB + 6291456;
    short* omtb= KaB + 6291456;             // 131,072    [h][m][d]

    conv_kernel<<<6272, 256, 0, stream>>>(hs, Wq, Wk, Wv, Wo, omega,
                                          hsb, wqb, wkb, wvb, wob, omtb);
    gemm_mfma<<<dim3(8, 16, 3), 256, 0, stream>>>(hsb, wqb, bq, qb, wkb, bk, kb, wvb, bv, vtb,
                                                  0, 0, 1, S_LEN);
    phi2_kernel<<<dim3(32, 16, 2), 256, 0, stream>>>(qb, kb, omtb, rffb, QaB, KaB);
    flash_mfma<<<dim3(32, 16), 256, 0, stream>>>(QaB, KaB, vtb, mask, ctxb);
    gemm_mfma<<<dim3(8, 16, 1), 256, 0, stream>>>(ctxb, wob, bo, out, wob, bo, out, wob, bo, out,
                                                  2, 2, 2, S_LEN);
}

// Round 10
// 119.080 us; speedup vs baseline: 1.8264x; 1.1402x over previous
//
#include <hip/hip_runtime.h>
#include <math.h>

#define S_LEN 2048
#define HID   1024
#define NH    16
#define HD    64
#define NM    128
#define CAUG  192
#define NCH   32            // chunks (KC=32) per wave-group; 2 groups cover 2048

constexpr float ALPHA = 0.9f;

typedef __attribute__((ext_vector_type(8))) short bf16x8;
typedef __attribute__((ext_vector_type(4))) short bf16x4;
typedef __attribute__((ext_vector_type(4))) float f32x4;
typedef __attribute__((ext_vector_type(4))) int   int4v;

#define MFMA(a,b,c) __builtin_amdgcn_mfma_f32_16x16x32_bf16(a,b,c,0,0,0)

static __device__ inline short f2bf(float f) {
    unsigned u = __float_as_uint(f);
    u += 0x7fffu + ((u >> 16) & 1u);      // RNE
    return (short)(u >> 16);
}
static __device__ inline float bf2f(short s) {
    return __uint_as_float(((unsigned)(unsigned short)s) << 16);
}

// ---------------------------------------------------------------------------
// fp32 -> bf16 conversion: hs + 4 weights, float4-wide; tail range does the
// omega [h][d][m] -> om_t bf16 [h][m][d] transpose.
// ---------------------------------------------------------------------------
__global__ __launch_bounds__(256)
void conv_kernel(const float* __restrict__ hs,
                 const float* __restrict__ Wq, const float* __restrict__ Wk,
                 const float* __restrict__ Wv, const float* __restrict__ Wo,
                 const float* __restrict__ omega,
                 short* __restrict__ hsb, short* __restrict__ wqb, short* __restrict__ wkb,
                 short* __restrict__ wvb, short* __restrict__ wob, short* __restrict__ omtb)
{
    int i = blockIdx.x * 256 + threadIdx.x;           // f4-unit index
    if (i >= 1605632) return;
    if (i >= 1572864) {                               // omega transpose tail
        int j = (i - 1572864) * 4;                    // elem index in [h][d][m]
        int h = j >> 13, rem = j & 8191;
        int d = rem >> 7, m = rem & 127;
        float4 v = *(const float4*)(omega + j);       // 4 consecutive m
        short* dst = omtb + ((h * 128 + m) << 6) + d; // [h][m][d]
        dst[0]       = f2bf(v.x);
        dst[64]      = f2bf(v.y);
        dst[128]     = f2bf(v.z);
        dst[192]     = f2bf(v.w);
        return;
    }
    const float* src; short* dst; int off;
    if (i < 524288) { src = hs; dst = hsb; off = i; }
    else {
        int j = i - 524288;
        int r = j >> 18;              // 0..3
        off = j & 262143;
        src = (r == 0) ? Wq : (r == 1) ? Wk : (r == 2) ? Wv : Wo;
        dst = (r == 0) ? wqb : (r == 1) ? wkb : (r == 2) ? wvb : wob;
    }
    float4 v = ((const float4*)src)[off];
    bf16x4 o; o[0] = f2bf(v.x); o[1] = f2bf(v.y); o[2] = f2bf(v.z); o[3] = f2bf(v.w);
    ((bf16x4*)dst)[off] = o;
}

// ---------------------------------------------------------------------------
// bf16 MFMA GEMM: C = A(2048x1024) @ W(1024x1024)^T + bias
// BM=64, BN=128, BK=32; 4 waves 2(m)x2(n), wave tile 32x64, acc[2][4].
// QKV grid (8,32,3)=768 blocks = 3/CU;  out-proj grid (8,32,1)=256 = 1/CU.
// mode 0: C bf16 [m][1024];  mode 1: C bf16 transposed [n][Mrows];  mode 2: C f32
// ---------------------------------------------------------------------------
__global__ __launch_bounds__(256)
void gemm_mfma(const short* __restrict__ A,
               const short* __restrict__ W0, const float* __restrict__ b0, void* C0,
               const short* __restrict__ W1, const float* __restrict__ b1, void* C1,
               const short* __restrict__ W2, const float* __restrict__ b2, void* C2,
               int m0_, int m1_, int m2_, int Mrows)
{
    const short* W; const float* bias; void* C; int mode;
    if (blockIdx.z == 0)      { W = W0; bias = b0; C = C0; mode = m0_; }
    else if (blockIdx.z == 1) { W = W1; bias = b1; C = C1; mode = m1_; }
    else                      { W = W2; bias = b2; C = C2; mode = m2_; }

    __shared__ short As[64][40];     // 32 k-cols + 4 pad -> 80B rows
    __shared__ short Bs[128][40];

    const int tid = threadIdx.x;
    const int wave = tid >> 6, lane = tid & 63;
    const int l15 = lane & 15, l4 = lane >> 4;
    const int wm = wave >> 1, wn = wave & 1;
    const int m0 = blockIdx.y * 64, n0 = blockIdx.x * 128;

    const int srow = tid >> 2;            // 0..63
    const int scol = (tid & 3) * 16;      // byte col within 64B k-row

    f32x4 acc[2][4];
#pragma unroll
    for (int i = 0; i < 2; ++i)
#pragma unroll
        for (int j = 0; j < 4; ++j) acc[i][j] = (f32x4){0.f,0.f,0.f,0.f};

    int4v apre, bpre0, bpre1;
    apre  = *(const int4v*)((const char*)A + (size_t)(m0 + srow) * 2048 + scol);
    bpre0 = *(const int4v*)((const char*)W + (size_t)(n0 + srow) * 2048 + scol);
    bpre1 = *(const int4v*)((const char*)W + (size_t)(n0 + 64 + srow) * 2048 + scol);

    for (int ks = 0; ks < 32; ++ks) {
        __syncthreads();
        *(int4v*)((char*)&As[0][0] + srow * 80 + scol) = apre;
        *(int4v*)((char*)&Bs[0][0] + srow * 80 + scol) = bpre0;
        *(int4v*)((char*)&Bs[0][0] + (64 + srow) * 80 + scol) = bpre1;
        __syncthreads();
        if (ks + 1 < 32) {
            const int kb = (ks + 1) * 64;
            apre  = *(const int4v*)((const char*)A + (size_t)(m0 + srow) * 2048 + kb + scol);
            bpre0 = *(const int4v*)((const char*)W + (size_t)(n0 + srow) * 2048 + kb + scol);
            bpre1 = *(const int4v*)((const char*)W + (size_t)(n0 + 64 + srow) * 2048 + kb + scol);
        }
        bf16x8 af[2], bf[4];
#pragma unroll
        for (int mi = 0; mi < 2; ++mi)
            af[mi] = *(const bf16x8*)((const char*)&As[0][0] + (wm*32 + mi*16 + l15) * 80 + l4*16);
#pragma unroll
        for (int nj = 0; nj < 4; ++nj)
            bf[nj] = *(const bf16x8*)((const char*)&Bs[0][0] + (wn*64 + nj*16 + l15) * 80 + l4*16);
#pragma unroll
        for (int mi = 0; mi < 2; ++mi)
#pragma unroll
            for (int nj = 0; nj < 4; ++nj)
                acc[mi][nj] = MFMA(af[mi], bf[nj], acc[mi][nj]);
    }

#pragma unroll
    for (int nj = 0; nj < 4; ++nj) {
        const int nglob = n0 + wn*64 + nj*16 + l15;
        const float bn = bias[nglob];
#pragma unroll
        for (int mi = 0; mi < 2; ++mi) {
            const int mbase = m0 + wm*32 + mi*16 + l4*4;
            if (mode == 0) {
#pragma unroll
                for (int r = 0; r < 4; ++r)
                    ((short*)C)[(size_t)(mbase + r) * 1024 + nglob] = f2bf(acc[mi][nj][r] + bn);
            } else if (mode == 1) {
                bf16x4 pk;
#pragma unroll
                for (int r = 0; r < 4; ++r) pk[r] = f2bf(acc[mi][nj][r] + bn);
                *(bf16x4*)((short*)C + (size_t)nglob * Mrows + mbase) = pk;
            } else {
#pragma unroll
                for (int r = 0; r < 4; ++r)
                    ((float*)C)[(size_t)(mbase + r) * 1024 + nglob] = acc[mi][nj][r] + bn;
            }
        }
    }
}

// ---------------------------------------------------------------------------
// phi2 (MFMA): per block = one (src, head, 64 s-rows)
// ---------------------------------------------------------------------------
__global__ __launch_bounds__(256)
void phi2_kernel(const short* __restrict__ qbuf, const short* __restrict__ kbuf,
                 const short* __restrict__ omtb, const float* __restrict__ rffb,
                 short* __restrict__ Qa, short* __restrict__ Ka)
{
    __shared__ short om[128][72];
    __shared__ float bsh[128];

    const int src = blockIdx.z, h = blockIdx.y;
    const int s0 = blockIdx.x * 64;
    const short* X = src ? kbuf : qbuf;
    short* Out     = src ? Ka : Qa;
    const float fq   = src ? 1.0f : (ALPHA * 0.125f);
    const float fphi = src ? 1.0f : ((1.0f - ALPHA) * 0.125f);

    const int tid = threadIdx.x, wave = tid >> 6, lane = tid & 63;
    const int l15 = lane & 15, l4 = lane >> 4;

    {
        const char* gsrc = (const char*)(omtb + ((size_t)h << 13));
#pragma unroll
        for (int it = 0; it < 4; ++it) {
            int f = tid * 16 + it * 4096;
            int row = f >> 7, colb = f & 127;
            *(int4v*)((char*)&om[0][0] + row * 144 + colb) = *(const int4v*)(gsrc + f);
        }
        if (tid < 128) bsh[tid] = rffb[h * 128 + tid];
    }
    __syncthreads();

    const int srow = s0 + wave * 16 + l15;

    bf16x8 xf[2];
#pragma unroll
    for (int cs = 0; cs < 2; ++cs)
        xf[cs] = *(const bf16x8*)(X + (size_t)srow * HID + h * HD + cs * 32 + l4 * 8);

    float ss = 0.f;
#pragma unroll
    for (int cs = 0; cs < 2; ++cs)
#pragma unroll
        for (int j = 0; j < 8; ++j) { float v = bf2f(xf[cs][j]); ss = fmaf(v, v, ss); }
    ss += __shfl_xor(ss, 16);
    ss += __shfl_xor(ss, 32);
    const float inv = 1.0f / (sqrtf(ss) + 1e-6f);

    bf16x8 qn[2];
#pragma unroll
    for (int cs = 0; cs < 2; ++cs) {
        bf16x8 o, w;
#pragma unroll
        for (int j = 0; j < 8; ++j) {
            float v = bf2f(xf[cs][j]);
            o[j] = f2bf(v * inv);
            w[j] = f2bf(v * fq);
        }
        qn[cs] = o;
        *(bf16x8*)(Out + ((size_t)h * S_LEN + srow) * CAUG + cs * 32 + l4 * 8) = w;
    }

    f32x4 pacc[8];
#pragma unroll
    for (int t = 0; t < 8; ++t) pacc[t] = (f32x4){0.f,0.f,0.f,0.f};
#pragma unroll
    for (int t = 0; t < 8; ++t)
#pragma unroll
        for (int cs = 0; cs < 2; ++cs) {
            bf16x8 bf = *(const bf16x8*)((const char*)&om[0][0] + (t*16 + l15) * 144 + cs*64 + l4*16);
            pacc[t] = MFMA(qn[cs], bf, pacc[t]);
        }

    float ph[8][4];
    float ps[4] = {0.f, 0.f, 0.f, 0.f};
#pragma unroll
    for (int t = 0; t < 8; ++t) {
        const float bv = bsh[t * 16 + l15];
#pragma unroll
        for (int r = 0; r < 4; ++r) {
            float p = pacc[t][r] + bv;
            float c = 0.125f * __cosf(p);
            ph[t][r] = c;
            ps[r] = fmaf(c, c, ps[r]);
        }
    }
#pragma unroll
    for (int r = 0; r < 4; ++r) {
        ps[r] += __shfl_xor(ps[r], 1);
        ps[r] += __shfl_xor(ps[r], 2);
        ps[r] += __shfl_xor(ps[r], 4);
        ps[r] += __shfl_xor(ps[r], 8);
    }
    float inv2[4];
#pragma unroll
    for (int r = 0; r < 4; ++r) inv2[r] = fphi / (sqrtf(ps[r]) + 1e-6f);

#pragma unroll
    for (int t = 0; t < 8; ++t)
#pragma unroll
        for (int r = 0; r < 4; ++r)
            Out[((size_t)h * S_LEN + s0 + wave * 16 + l4 * 4 + r) * CAUG + 64 + t * 16 + l15]
                = f2bf(ph[t][r] * inv2[r]);
}

// ---------------------------------------------------------------------------
// MFMA flash attention, SOFTWARE-PIPELINED (R6 structure + deferred softmax):
// per iteration: stage chunk i -> issue scores(i) MFMA -> prefetch i+1 (global)
// -> softmax+PV of chunk i-1 on the VALU while scores(i) MFMAs drain.
// 2 wave-groups x 2 waves (32 q each, qj=2); K single-buffered per group
// (read only by scores between the two barriers); V double-buffered in LDS
// (read one chunk late by the deferred PV).  Static-max softmax.
// Grid 32x16 = 512 blocks = 2 blocks/CU (56.3 KB LDS).
// ---------------------------------------------------------------------------
__global__ __launch_bounds__(256, 2)
void flash_mfma(const short* __restrict__ Qa, const short* __restrict__ Ka,
                const short* __restrict__ vt, const float* __restrict__ mask,
                short* __restrict__ ctxb)
{
    // layout:
    //   [0,10240):      Pl[4][32][80B]   per-wave P slabs
    //   [10240,35840):  Kbuf[group][12800]  (single buffer per group)
    //   [35840,56320):  Vt[group][2][64][80B]  (double-buffered V^T)
    //   combine scratch: scrO f32[2][32][68] @ 10240, scrL @ 27648
    __shared__ char smem[56320];

    const int tid = threadIdx.x;
    const int wave = tid >> 6, lane = tid & 63;
    const int l15 = lane & 15, l4 = lane >> 4;
    const int g = wave >> 1, sub = wave & 1;
    const int h = blockIdx.y;
    const int q0 = blockIdx.x * 64 + sub * 32;

    char* PlW  = smem + wave * 2560;
    char* Kbuf = smem + 10240 + g * 12800;
    char* Vt0  = smem + 35840 + g * 10240;
    char* Vt1  = Vt0 + 5120;

    // Q' fragments: 32 q rows per wave
    bf16x8 qf[2][6];
#pragma unroll
    for (int qj = 0; qj < 2; ++qj)
#pragma unroll
        for (int cs = 0; cs < 6; ++cs)
            qf[qj][cs] = *(const bf16x8*)(Qa + ((size_t)h * 2048 + q0 + qj*16 + l15) * CAUG + cs*32 + l4*8);

    f32x4 oacc[4][2];
#pragma unroll
    for (int di = 0; di < 4; ++di)
#pragma unroll
        for (int qj = 0; qj < 2; ++qj) oacc[di][qj] = (f32x4){0.f,0.f,0.f,0.f};
    float lsum[2] = {0.f, 0.f};

    // staging geometry: 128 threads of the group; K 12288B (6x16B), V 4096B (2x16B)
    const int t = tid & 127;
    int kr[6], kcb[6], vr[2], vcb[2];
#pragma unroll
    for (int it = 0; it < 6; ++it) { int f = t*16 + it*2048; kr[it] = f/384; kcb[it] = f%384; }
#pragma unroll
    for (int it = 0; it < 2; ++it) { int f = t*16 + it*2048; vr[it] = f/64; vcb[it] = f%64; }

    const char* Kg = (const char*)(Ka + (size_t)h * 2048 * CAUG);   // rows 384B
    const char* Vg = (const char*)(vt + (size_t)h * 64 * 2048);     // rows 4096B
    const int base = g * NCH;

    int4v kpre[6], vpre[2];
    auto loadPre = [&](int kt) {
        const char* kb = Kg + (size_t)kt * 12288;
#pragma unroll
        for (int it = 0; it < 6; ++it)
            kpre[it] = *(const int4v*)(kb + (size_t)kr[it]*384 + kcb[it]);
#pragma unroll
        for (int it = 0; it < 2; ++it)
            vpre[it] = *(const int4v*)(Vg + (size_t)vr[it]*4096 + kt*64 + vcb[it]);
    };

    // pipelined state (chunk i-1)
    f32x4 sacc_p[2][2];
    float4 mkp0, mkp1;

    auto softmax_pv = [&](char* Vbuf) {
        // ---- static-max softmax on sacc_p ----
#pragma unroll
        for (int fi = 0; fi < 2; ++fi) {
            const float4 mk = fi ? mkp1 : mkp0;
            float mv[4] = {mk.x * -10000.f, mk.y * -10000.f, mk.z * -10000.f, mk.w * -10000.f};
#pragma unroll
            for (int qj = 0; qj < 2; ++qj) {
                bf16x4 pk;
#pragma unroll
                for (int r = 0; r < 4; ++r) {
                    float p = __expf(sacc_p[fi][qj][r] + mv[r]);
                    lsum[qj] += p;
                    pk[r] = f2bf(p);
                }
                *(bf16x4*)(PlW + (qj*16 + l15)*80 + fi*32 + l4*8) = pk;
            }
        }
        // ---- PV: O^T += V^T . P^T ----
        bf16x8 va[4], pb[2];
#pragma unroll
        for (int di = 0; di < 4; ++di)
            va[di] = *(const bf16x8*)(Vbuf + (di*16 + l15)*80 + l4*16);
#pragma unroll
        for (int qj = 0; qj < 2; ++qj)
            pb[qj] = *(const bf16x8*)(PlW + (qj*16 + l15)*80 + l4*16);
#pragma unroll
        for (int di = 0; di < 4; ++di)
#pragma unroll
            for (int qj = 0; qj < 2; ++qj)
                oacc[di][qj] = MFMA(va[di], pb[qj], oacc[di][qj]);
    };

    // prologue: load chunk base into staging regs
    loadPre(base);

    for (int i = 0; i < NCH; ++i) {
        const int kt = base + i;
        char* Vcur = (i & 1) ? Vt1 : Vt0;
        __syncthreads();                    // prev scores + PV(i-2) LDS reads done
#pragma unroll
        for (int it = 0; it < 6; ++it)
            *(int4v*)(Kbuf + kr[it]*400 + kcb[it]) = kpre[it];
#pragma unroll
        for (int it = 0; it < 2; ++it)
            *(int4v*)(Vcur + vr[it]*80 + vcb[it]) = vpre[it];
        __syncthreads();                    // chunk i staged

        // ---- issue scores(i) MFMAs ----
        f32x4 sc[2][2];
#pragma unroll
        for (int fi = 0; fi < 2; ++fi)
#pragma unroll
            for (int qj = 0; qj < 2; ++qj) sc[fi][qj] = (f32x4){0.f,0.f,0.f,0.f};
#pragma unroll
        for (int cs = 0; cs < 6; ++cs) {
            bf16x8 ka[2];
#pragma unroll
            for (int fi = 0; fi < 2; ++fi)
                ka[fi] = *(const bf16x8*)(Kbuf + (fi*16 + l15)*400 + cs*64 + l4*16);
#pragma unroll
            for (int fi = 0; fi < 2; ++fi)
#pragma unroll
                for (int qj = 0; qj < 2; ++qj)
                    sc[fi][qj] = MFMA(ka[fi], qf[qj][cs], sc[fi][qj]);
        }
        // mask for chunk i (consumed next iteration)
        float4 mkc0 = *(const float4*)&mask[kt*32 + l4*4];
        float4 mkc1 = *(const float4*)&mask[kt*32 + 16 + l4*4];

        // ---- prefetch chunk i+1 (global; latency hides under VALU below) ----
        if (i + 1 < NCH) loadPre(kt + 1);

        // ---- softmax + PV of chunk i-1 on the VALU while scores(i) drain ----
        if (i > 0) softmax_pv((i & 1) ? Vt0 : Vt1);

        // rotate pipelined state
#pragma unroll
        for (int fi = 0; fi < 2; ++fi)
#pragma unroll
            for (int qj = 0; qj < 2; ++qj) sacc_p[fi][qj] = sc[fi][qj];
        mkp0 = mkc0; mkp1 = mkc1;
    }
    // tail: finish last chunk (parity NCH-1 odd -> Vt1)
    softmax_pv(Vt1);

    // reduce l across the 4 kpos lane-groups
#pragma unroll
    for (int qj = 0; qj < 2; ++qj) {
        lsum[qj] += __shfl_xor(lsum[qj], 16);
        lsum[qj] += __shfl_xor(lsum[qj], 32);
    }

    // ---- combine the two K-groups via LDS scratch (reuse Kbuf region) ----
    __syncthreads();                        // all groups done with Kbuf/Vt
    float* scrO = (float*)(smem + 10240);   // [2][32][68] f32
    float* scrL = (float*)(smem + 27648);   // [2][32]
    if (g == 1) {
#pragma unroll
        for (int qj = 0; qj < 2; ++qj) {
#pragma unroll
            for (int di = 0; di < 4; ++di)
                *(f32x4*)&scrO[(size_t)(sub*32 + qj*16 + l15)*68 + di*16 + l4*4] = oacc[di][qj];
            if (l4 == 0) scrL[sub*32 + qj*16 + l15] = lsum[qj];
        }
    }
    __syncthreads();
    if (g == 0) {
#pragma unroll
        for (int qj = 0; qj < 2; ++qj) {
            const float l = lsum[qj] + scrL[sub*32 + qj*16 + l15];
            const float inv = 1.0f / l;
            const int s = q0 + qj*16 + l15;
#pragma unroll
            for (int di = 0; di < 4; ++di) {
                f32x4 o2 = *(const f32x4*)&scrO[(size_t)(sub*32 + qj*16 + l15)*68 + di*16 + l4*4];
                bf16x4 ob;
#pragma unroll
                for (int r = 0; r < 4; ++r) ob[r] = f2bf((oacc[di][qj][r] + o2[r]) * inv);
                *(bf16x4*)(ctxb + (size_t)s * HID + h*64 + di*16 + l4*4) = ob;
            }
        }
    }
}

// ---------------------------------------------------------------------------
extern "C" void kernel_launch(void* const* d_in, const int* in_sizes, int n_in,
                              void* d_out, int out_size, void* d_ws, size_t ws_size,
                              hipStream_t stream)
{
    const float* hs    = (const float*)d_in[0];
    const float* mask  = (const float*)d_in[1];
    const float* Wq    = (const float*)d_in[2];
    const float* bq    = (const float*)d_in[3];
    const float* Wk    = (const float*)d_in[4];
    const float* bk    = (const float*)d_in[5];
    const float* Wv    = (const float*)d_in[6];
    const float* bv    = (const float*)d_in[7];
    const float* Wo    = (const float*)d_in[8];
    const float* bo    = (const float*)d_in[9];
    const float* omega = (const float*)d_in[10];
    const float* rffb  = (const float*)d_in[11];
    float* out = (float*)d_out;

    short* wsS = (short*)d_ws;
    short* hsb = wsS;                       // 2,097,152
    short* wqb = hsb + 2097152;             // 1,048,576
    short* wkb = wqb + 1048576;
    short* wvb = wkb + 1048576;
    short* wob = wvb + 1048576;
    short* qb  = wob + 1048576;             // 2,097,152
    short* kb  = qb  + 2097152;
    short* vtb = kb  + 2097152;             // 2,097,152  [h][d][s]
    short* ctxb= vtb + 2097152;             // 2,097,152
    short* QaB = ctxb+ 2097152;             // 6,291,456  [h][s][192]
    short* KaB = QaB + 6291456;
    short* omtb= KaB + 6291456;             // 131,072    [h][m][d]

    conv_kernel<<<6272, 256, 0, stream>>>(hs, Wq, Wk, Wv, Wo, omega,
                                          hsb, wqb, wkb, wvb, wob, omtb);
    gemm_mfma<<<dim3(8, 32, 3), 256, 0, stream>>>(hsb, wqb, bq, qb, wkb, bk, kb, wvb, bv, vtb,
                                                  0, 0, 1, S_LEN);
    phi2_kernel<<<dim3(32, 16, 2), 256, 0, stream>>>(qb, kb, omtb, rffb, QaB, KaB);
    flash_mfma<<<dim3(32, 16), 256, 0, stream>>>(QaB, KaB, vtb, mask, ctxb);
    gemm_mfma<<<dim3(8, 32, 1), 256, 0, stream>>>(ctxb, wob, bo, out, wob, bo, out, wob, bo, out,
                                                  2, 2, 2, S_LEN);
}